// Round 10
// baseline (203.768 us; speedup 1.0000x reference)
//
#include <hip/hip_runtime.h>
#include <stdint.h>

#define HIDDEN 1536
#define NHEAD 12
#define HD 128
#define TSEQ 2048
#define NROWS 4096
#define KDIM HIDDEN
#define EPS_F 1.1920928955078125e-07f
// (1/sqrt(128)) * log2(e)
#define SCALE_LOG2E 0.12751879110195655f
// fixed softmax shift (log2 domain): scores bounded by sqrt(128)=11.314 (RMS-normed
// q,k => |q||k|<=128 by Cauchy-Schwarz), *log2(e) = 16.32; use 16.6 for bf16 margin.
#define FIXSUB 16.6f

typedef unsigned short u16;
typedef __bf16 bf16x8_t __attribute__((ext_vector_type(8)));
typedef float f32x4_t __attribute__((ext_vector_type(4)));

#define MFMA16(a, b, c) __builtin_amdgcn_mfma_f32_16x16x32_bf16((a), (b), (c), 0, 0, 0)
#define GLL(srcp, dstp) \
  __builtin_amdgcn_global_load_lds((const __attribute__((address_space(1))) void*)(srcp), \
                                   (__attribute__((address_space(3))) void*)(dstp), 16, 0, 0)

__device__ __forceinline__ u16 f2bf(float f) {
  unsigned u = __builtin_bit_cast(unsigned, f);
  u = (u + 0x7fffu + ((u >> 16) & 1u)) >> 16;
  return (u16)u;
}
__device__ __forceinline__ float bfu(u16 v) {
  return __builtin_bit_cast(float, ((unsigned)v) << 16);
}

// ---------------- cast fp32 -> bf16 (vectorized) ----------------
__global__ __launch_bounds__(256) void cast_kernel(const float* __restrict__ in,
                                                   u16* __restrict__ out, int n) {
  int i = (blockIdx.x * 256 + threadIdx.x) * 4;
  if (i >= n) return;
  float4 v = *reinterpret_cast<const float4*>(in + i);
  uint2 pk;
  pk.x = (unsigned)f2bf(v.x) | ((unsigned)f2bf(v.y) << 16);
  pk.y = (unsigned)f2bf(v.z) | ((unsigned)f2bf(v.w) << 16);
  *reinterpret_cast<uint2*>(out + i) = pk;
}

// 4 equal-size weight casts in one launch (blockIdx.y selects)
__global__ __launch_bounds__(256) void cast4_kernel(
    const float* __restrict__ a, const float* __restrict__ b, const float* __restrict__ c,
    const float* __restrict__ d, u16* __restrict__ oa, u16* __restrict__ ob,
    u16* __restrict__ oc, u16* __restrict__ od, int n) {
  const float* in;
  u16* out;
  switch (blockIdx.y) {
    case 0: in = a; out = oa; break;
    case 1: in = b; out = ob; break;
    case 2: in = c; out = oc; break;
    default: in = d; out = od; break;
  }
  int i = (blockIdx.x * 256 + threadIdx.x) * 4;
  if (i >= n) return;
  float4 v = *reinterpret_cast<const float4*>(in + i);
  uint2 pk;
  pk.x = (unsigned)f2bf(v.x) | ((unsigned)f2bf(v.y) << 16);
  pk.y = (unsigned)f2bf(v.z) | ((unsigned)f2bf(v.w) << 16);
  *reinterpret_cast<uint2*>(out + i) = pk;
}

// ---------------- QKV: phase-pipelined 256x128 GEMM + fused RoPE/RMS epilogue ----------------
// BM=256, BN=128(=HD), BK=64. 512 threads = 8 waves (4M x 2N), 64x64 out/wave.
// 96KB LDS: buf b at b*24576 u16: A-half0 [0,8K) A-half1 [8K,16K) B [16K,24K).
// Per K-tile, 2 phases of 16 MFMA each; stages (into the OTHER buffer) split
// across phases: A0,A1 at phase 0, B at phase 1; single vmcnt(0) AFTER phase-1's
// MFMA cluster -> every load gets >=1 phase (~620cy) of latency cover. setprio
// wraps MFMA clusters (T5). XOR-swizzled LDS via pre-swizzled global source.
__global__ __launch_bounds__(512, 2) void gemm_qkv_kernel(
    const u16* __restrict__ xb, const u16* __restrict__ wq, const u16* __restrict__ wk,
    const u16* __restrict__ wv, const float* __restrict__ cosp, const float* __restrict__ sinp,
    u16* __restrict__ qh, u16* __restrict__ kh, u16* __restrict__ vt) {
  __shared__ __align__(16) u16 lds[49152];  // 96 KiB
  const int tid = threadIdx.x;
  const int bid = blockIdx.x;              // 576 = 8 XCD x 72
  const int xcd = bid & 7, cc = bid >> 3;  // 0..71
  const int m = xcd * 2 + (cc & 1);        // 0..15  (m-pair per XCD: A-band L2-hot)
  const int nz = cc >> 1;                  // 0..35
  const int z = nz / 12, n = nz % 12;      // weight select / head
  const int M0 = m * 256, N0 = n * 128;
  const u16* W = (z == 0) ? wq : (z == 1) ? wk : wv;
  const int w = tid >> 6, l = tid & 63;
  const int lrow = l & 15, kg = l >> 4;
  const int wm = w >> 1, wn = w & 1;
  // ---- staging: half-tile = 128 rows x 64 cols bf16 = 1024 chunks; 2 chunks/thread
  const int srow = tid >> 3;  // 0..63 (+64 for second chunk)
  const unsigned jsw = (unsigned)(((tid & 7) ^ (srow & 7)) * 8);  // pre-swizzled col-chunk
  const u16* pA0 = xb + (size_t)(M0 + srow) * KDIM + jsw;
  const u16* pA1 = xb + (size_t)(M0 + 128 + srow) * KDIM + jsw;
  const u16* pB = W + (size_t)(N0 + srow) * KDIM + jsw;
  const size_t R64 = (size_t)64 * KDIM;
  u16* dst0 = lds + w * 512;  // wave-uniform; HW adds lane*16B
  auto stage = [&](const u16* p, int buf, int i) {
    u16* db = dst0 + buf * 24576 + i * 8192;
    GLL(p, db);
    GLL(p + R64, db + 4096);
  };
  // prologue: tile 0 -> buf 0
  stage(pA0, 0, 0);
  stage(pA1, 0, 1);
  stage(pB, 0, 2);
  pA0 += 64; pA1 += 64; pB += 64;
  asm volatile("s_waitcnt vmcnt(0)" ::: "memory");
  __builtin_amdgcn_s_barrier();
  asm volatile("" ::: "memory");
  f32x4_t acc[4][4] = {};
  const int aoff = (wm >> 1) * 8192;   // which A-half this wave reads
  const int arow0 = (wm & 1) * 64;     // row base within the half
  const int swz = lrow & 7;
  const int NT = KDIM / 64;  // 24
#pragma unroll 1
  for (int T = 0; T < NT; ++T) {
    const int buf = T & 1;
    const u16* Ab = lds + buf * 24576 + aoff;
    const u16* Bb = lds + buf * 24576 + 16384;
    // ================ phase 0: B-frags + A mf{0,1}; stage A0,A1(next) ================
    bf16x8_t bfr[4][2], afr[2][2];
#pragma unroll
    for (int nf = 0; nf < 4; ++nf)
#pragma unroll
      for (int ks = 0; ks < 2; ++ks)
        bfr[nf][ks] = *reinterpret_cast<const bf16x8_t*>(
            Bb + (wn * 64 + nf * 16 + lrow) * 64 + (((ks << 2) | kg) ^ swz) * 8);
#pragma unroll
    for (int mf = 0; mf < 2; ++mf)
#pragma unroll
      for (int ks = 0; ks < 2; ++ks)
        afr[mf][ks] = *reinterpret_cast<const bf16x8_t*>(
            Ab + (arow0 + mf * 16 + lrow) * 64 + (((ks << 2) | kg) ^ swz) * 8);
    if (T + 1 < NT) {
      stage(pA0, buf ^ 1, 0);
      stage(pA1, buf ^ 1, 1);
    }
    __builtin_amdgcn_s_barrier();
    asm volatile("" ::: "memory");
    __builtin_amdgcn_s_setprio(1);
#pragma unroll
    for (int mf = 0; mf < 2; ++mf)
#pragma unroll
      for (int nf = 0; nf < 4; ++nf)
#pragma unroll
        for (int ks = 0; ks < 2; ++ks)
          acc[mf][nf] = MFMA16(afr[mf][ks], bfr[nf][ks], acc[mf][nf]);
    __builtin_amdgcn_s_setprio(0);
    __builtin_amdgcn_s_barrier();
    asm volatile("" ::: "memory");
    // ================ phase 1: A mf{2,3}; stage B(next); drain ================
    bf16x8_t afr2[2][2];
#pragma unroll
    for (int mf = 0; mf < 2; ++mf)
#pragma unroll
      for (int ks = 0; ks < 2; ++ks)
        afr2[mf][ks] = *reinterpret_cast<const bf16x8_t*>(
            Ab + (arow0 + (mf + 2) * 16 + lrow) * 64 + (((ks << 2) | kg) ^ swz) * 8);
    if (T + 1 < NT) {
      stage(pB, buf ^ 1, 2);
      pA0 += 64; pA1 += 64; pB += 64;
    }
    __builtin_amdgcn_s_barrier();
    asm volatile("" ::: "memory");
    __builtin_amdgcn_s_setprio(1);
#pragma unroll
    for (int mf = 0; mf < 2; ++mf)
#pragma unroll
      for (int nf = 0; nf < 4; ++nf)
#pragma unroll
        for (int ks = 0; ks < 2; ++ks)
          acc[mf + 2][nf] = MFMA16(afr2[mf][ks], bfr[nf][ks], acc[mf + 2][nf]);
    __builtin_amdgcn_s_setprio(0);
    asm volatile("s_waitcnt vmcnt(0)" ::: "memory");  // next tile landed; >=1 phase of cover
    __builtin_amdgcn_s_barrier();
    asm volatile("" ::: "memory");
  }
  // ---- epilogue: stage C (bf16, swizzled) in LDS; rope/rms (z<2) or transpose (z=2) ----
  char* cs = reinterpret_cast<char*>(lds);
  const int bb = M0 >> 11;  // batch (256-row tile never straddles: 2048%256==0)
  const int t0 = M0 & (TSEQ - 1);
  const size_t bhn = (size_t)(bb * NHEAD + n);
  if (z == 2) {
    // [d(128)][t(256)] rows of 512B, XOR (d&7) on 16B-chunk index
#pragma unroll
    for (int mf = 0; mf < 4; ++mf)
#pragma unroll
      for (int nf = 0; nf < 4; ++nf)
#pragma unroll
        for (int r = 0; r < 4; ++r) {
          const int trow = wm * 64 + mf * 16 + kg * 4 + r;
          const int d = wn * 64 + nf * 16 + lrow;
          const int bofs = (d * 512 + trow * 2) ^ ((d & 7) << 4);
          *reinterpret_cast<u16*>(cs + bofs) = f2bf(acc[mf][nf][r]);
        }
    __syncthreads();
    const int d = tid >> 2, tq = tid & 3;  // 128 d x 4 t-quarters
    u16* dst = vt + (bhn * HD + d) * TSEQ + t0 + tq * 64;
    const char* rb = cs + d * 512 + tq * 128;
#pragma unroll
    for (int j = 0; j < 8; ++j) {
      uint4 v = *reinterpret_cast<const uint4*>(rb + ((j ^ (d & 7)) * 16));
      *reinterpret_cast<uint4*>(dst + j * 8) = v;
    }
  } else {
    // [t(256)][d(128)] rows of 256B, XOR (t&7) on 16B-chunk index
#pragma unroll
    for (int mf = 0; mf < 4; ++mf)
#pragma unroll
      for (int nf = 0; nf < 4; ++nf)
#pragma unroll
        for (int r = 0; r < 4; ++r) {
          const int trow = wm * 64 + mf * 16 + kg * 4 + r;
          const int d = wn * 64 + nf * 16 + lrow;
          const int bofs = (trow * 256 + d * 2) ^ ((trow & 7) << 4);
          *reinterpret_cast<u16*>(cs + bofs) = f2bf(acc[mf][nf][r]);
        }
    __syncthreads();
    const int rr = tid >> 1, hh = tid & 1;  // 256 rows x 2 d-halves
    const int t = t0 + rr;
    const float* cosb = cosp + t * 64;
    const float* sinb = sinp + t * 64;
    const char* base = cs + rr * 256;
    float ss = 0.0f;
    unsigned pk[32];  // 64 rope'd values packed bf16x2
#pragma unroll
    for (int j = 0; j < 8; ++j) {
      const int jp = (j ^ (rr & 7)) * 16;
      uint4 vo = *reinterpret_cast<const uint4*>(base + hh * 128 + jp);        // own half
      uint4 vx = *reinterpret_cast<const uint4*>(base + (hh ^ 1) * 128 + jp);  // other half
      const unsigned vo32[4] = {vo.x, vo.y, vo.z, vo.w};
      const unsigned vx32[4] = {vx.x, vx.y, vx.z, vx.w};
      const float* cj = cosb + j * 8;
      const float* sj = sinb + j * 8;
#pragma unroll
      for (int q2 = 0; q2 < 4; ++q2) {
        float o0 = bfu((u16)(vo32[q2] & 0xffffu)), o1 = bfu((u16)(vo32[q2] >> 16));
        float x0 = bfu((u16)(vx32[q2] & 0xffffu)), x1 = bfu((u16)(vx32[q2] >> 16));
        float cc0 = cj[q2 * 2], cc1 = cj[q2 * 2 + 1];
        float s0 = sj[q2 * 2], s1 = sj[q2 * 2 + 1];
        // hh=0: y = x1*cos + x2*sin ; hh=1: y = x2*cos - x1*sin
        float y0 = hh ? __builtin_fmaf(o0, cc0, -x0 * s0) : __builtin_fmaf(o0, cc0, x0 * s0);
        float y1 = hh ? __builtin_fmaf(o1, cc1, -x1 * s1) : __builtin_fmaf(o1, cc1, x1 * s1);
        ss = __builtin_fmaf(y0, y0, __builtin_fmaf(y1, y1, ss));
        pk[j * 4 + q2] = (unsigned)f2bf(y0) | ((unsigned)f2bf(y1) << 16);
      }
    }
    ss += __shfl_xor(ss, 1, 64);  // partner thread holds the other half of this row
    const float rinv = rsqrtf(ss * (1.0f / 128.0f) + EPS_F);
    u16* dst = ((z == 0) ? qh : kh) + (bhn * TSEQ + t) * HD + hh * 64;
#pragma unroll
    for (int j = 0; j < 8; ++j) {
      unsigned o[4];
#pragma unroll
      for (int q2 = 0; q2 < 4; ++q2) {
        float y0 = bfu((u16)(pk[j * 4 + q2] & 0xffffu)) * rinv;
        float y1 = bfu((u16)(pk[j * 4 + q2] >> 16)) * rinv;
        o[q2] = (unsigned)f2bf(y0) | ((unsigned)f2bf(y1) << 16);
      }
      uint4 v;
      v.x = o[0]; v.y = o[1]; v.z = o[2]; v.w = o[3];
      *reinterpret_cast<uint4*>(dst + j * 8) = v;
    }
  }
}

// ---------------- shared NT-GEMM mainloop, BK=64 (R8-proven; used by gemm_out) ----------------
__device__ __forceinline__ void gemm_mainloop64(const u16* __restrict__ A,
                                                const u16* __restrict__ W, int M0, int N0,
                                                u16* lds, f32x4_t acc[4][4], int tid) {
  const int w = tid >> 6, l = tid & 63;
  const int lrow = l & 15, kg = l >> 4;
  const int wr = (w >> 1) * 64, wc = (w & 1) * 64;
  const int row0 = tid >> 3, j0 = tid & 7;
  const unsigned jsw = (unsigned)((j0 ^ (row0 & 7)) * 8);
  unsigned offA = (unsigned)((M0 + row0) * KDIM) + jsw;
  unsigned offW = (unsigned)((N0 + row0) * KDIM) + jsw;
  const u16* A1 = A + 32 * KDIM; const u16* A2 = A + 64 * KDIM; const u16* A3 = A + 96 * KDIM;
  const u16* W1 = W + 32 * KDIM; const u16* W2 = W + 64 * KDIM; const u16* W3 = W + 96 * KDIM;
  auto issue = [&](int buf) {
    u16* da = lds + buf * 8192 + w * 512;
    u16* dw = lds + 16384 + buf * 8192 + w * 512;
    GLL(A + offA, da);          GLL(A1 + offA, da + 2048);
    GLL(A2 + offA, da + 4096);  GLL(A3 + offA, da + 6144);
    GLL(W + offW, dw);          GLL(W1 + offW, dw + 2048);
    GLL(W2 + offW, dw + 4096);  GLL(W3 + offW, dw + 6144);
    offA += 64; offW += 64;
  };
  issue(0);
  const int NT = KDIM / 64;  // 24
#pragma unroll 1
  for (int kt = 0; kt < NT; ++kt) {
    const int cur = kt & 1;
    if (kt + 1 < NT) {
      issue(cur ^ 1);
      asm volatile("s_waitcnt vmcnt(8)" ::: "memory");
    } else {
      asm volatile("s_waitcnt vmcnt(0)" ::: "memory");
    }
    __builtin_amdgcn_s_barrier();
    asm volatile("" ::: "memory");
    const u16* Ab = lds + cur * 8192;
    const u16* Wb = lds + 16384 + cur * 8192;
#pragma unroll
    for (int s = 0; s < 2; ++s) {
      bf16x8_t af[4], bf_[4];
#pragma unroll
      for (int mi = 0; mi < 4; ++mi) {
        const int row = wr + mi * 16 + lrow;
        af[mi] = *reinterpret_cast<const bf16x8_t*>(Ab + row * 64 +
                                                    (((s << 2) | kg) ^ (row & 7)) * 8);
      }
#pragma unroll
      for (int ni = 0; ni < 4; ++ni) {
        const int row = wc + ni * 16 + lrow;
        bf_[ni] = *reinterpret_cast<const bf16x8_t*>(Wb + row * 64 +
                                                     (((s << 2) | kg) ^ (row & 7)) * 8);
      }
#pragma unroll
      for (int mi = 0; mi < 4; ++mi)
#pragma unroll
        for (int ni = 0; ni < 4; ++ni)
          acc[mi][ni] = MFMA16(af[mi], bf_[ni], acc[mi][ni]);
    }
    asm volatile("s_waitcnt lgkmcnt(0)" ::: "memory");
    __builtin_amdgcn_s_barrier();
    asm volatile("" ::: "memory");
  }
}

// ---------------- output projection (flattened grid, XCD-chunked; R8-proven) ----------------
__global__ __launch_bounds__(256) void gemm_out_kernel(const u16* __restrict__ yh,
                                                       const u16* __restrict__ wp,
                                                       float* __restrict__ out) {
  __shared__ __align__(16) u16 lds[32768];
  const int tid = threadIdx.x;
  const int wgid = blockIdx.x;
  const int xcd = wgid & 7, c = wgid >> 3;
  const int m = ((xcd & 3) << 3) + (c & 7);
  const int n = ((xcd >> 2) * 6) + (c >> 3);
  const int M0 = m * 128, N0 = n * 128;
  f32x4_t acc[4][4] = {};
  gemm_mainloop64(yh, wp, M0, N0, lds, acc, tid);
  const int w = tid >> 6, l = tid & 63;
  const int lrow = l & 15, kg = l >> 4;
  const int wr = (w >> 1) * 64, wc = (w & 1) * 64;
#pragma unroll
  for (int mi = 0; mi < 4; ++mi)
#pragma unroll
    for (int ni = 0; ni < 4; ++ni)
#pragma unroll
      for (int r = 0; r < 4; ++r) {
        const int grow = M0 + wr + mi * 16 + kg * 4 + r;
        const int gcol = N0 + wc + ni * 16 + lrow;
        out[(size_t)grow * HIDDEN + gcol] = acc[mi][ni][r];
      }
}

// ---------------- flash attention: 2-barrier pipeline, dbuf K AND V (R9-proven) ----------------
__global__ __launch_bounds__(512, 4) void attn_kernel(const u16* __restrict__ qh,
                                                      const u16* __restrict__ kh,
                                                      const u16* __restrict__ vt,
                                                      u16* __restrict__ yh,
                                                      const int* __restrict__ winp) {
  __shared__ __align__(16) u16 Kl[2][8192];  // [buf][64 keys x 128 d], swizzled
  __shared__ __align__(16) u16 Vl[2][8192];  // [buf][128 d x 64 t], swizzled
  __shared__ __align__(16) u16 Pl[8][1024];  // per-wave 16x64 P, swizzled
  const int tid = threadIdx.x, w = tid >> 6, l = tid & 63;
  const int lrow = l & 15, kg = l >> 4;
  const int bid = blockIdx.x;  // 384 = 8 XCDs x 48
  const int swz = (bid & 7) * 48 + (bid >> 3);
  const int qb = swz & 15;  // q-block (128 rows) within (b,h)
  const int bh = swz >> 4;  // 0..23
  const int h = bh % NHEAD, b = bh / NHEAD;
  const int win = winp[0];
  const u16* Q = qh + (size_t)bh * TSEQ * HD;
  const u16* K = kh + (size_t)bh * TSEQ * HD;
  const u16* V = vt + (size_t)bh * HD * TSEQ;
  const int qw = qb * 128 + w * 16;  // this wave's 16 q-rows
  bf16x8_t aq[4];
#pragma unroll
  for (int ks = 0; ks < 4; ++ks)
    aq[ks] = *reinterpret_cast<const bf16x8_t*>(Q + (qw + lrow) * HD + ks * 32 + kg * 8);
  float lsum[4] = {0.f, 0.f, 0.f, 0.f};  // per-lane partial row sums (reduced post-loop)
  f32x4_t accv[8] = {};
  int lo = qb * 128 - win;
  if (lo < 0) lo = 0;
  lo &= ~63;
  const int last = qb * 128 + 64;  // last KV tile start (diagonal tile)

  u16* Pw = &Pl[w][0];

  auto stage_k = [&](int kv, int buf) {
#pragma unroll
    for (int i = 0; i < 2; ++i) {
      const int c = i * 512 + w * 64 + l;
      const int row = c >> 4, j = c & 15;
      const u16* src = K + (size_t)(kv + row) * HD + ((j ^ (row & 7)) * 8);
      GLL(src, &Kl[buf][0] + i * 4096 + w * 512);
    }
  };
  auto stage_v = [&](int kv, int buf) {
#pragma unroll
    for (int i = 0; i < 2; ++i) {
      const int c = i * 512 + w * 64 + l;
      const int row = c >> 3, j = c & 7;
      const u16* src = V + (size_t)row * TSEQ + kv + ((j ^ (row & 7)) * 8);
      GLL(src, &Vl[buf][0] + i * 4096 + w * 512);
    }
  };

  stage_k(lo, 0);
  stage_v(lo, 0);  // prologue: 4 loads in flight
  int it = 0;
  for (int kv = lo; kv <= last; kv += 64, ++it) {
    const int cur = it & 1;
    const int kpre = (kv + 64 <= last) ? kv + 64 : last;  // clamp tail prefetch
    stage_k(kpre, cur ^ 1);                               // +2 -> 6 outstanding
    asm volatile("s_waitcnt vmcnt(2)" ::: "memory");      // K(kv),V(kv) landed
    __builtin_amdgcn_s_barrier();                         // b1
    asm volatile("" ::: "memory");
    stage_v(kpre, cur ^ 1);  // +2 (Vl[cur^1] PV-reads all finished before b1)
    // ---- S = Q K^T (16 x 64) from LDS ----
    const u16* Kb = &Kl[cur][0];
    f32x4_t s[4] = {};
#pragma unroll
    for (int n = 0; n < 4; ++n) {
      const int row = n * 16 + lrow;
#pragma unroll
      for (int ks = 0; ks < 4; ++ks) {
        bf16x8_t bk = *reinterpret_cast<const bf16x8_t*>(
            Kb + row * 128 + (((ks << 2) | kg) ^ (row & 7)) * 8);
        s[n] = MFMA16(aq[ks], bk, s[n]);
      }
    }
    // ---- softmax: interior tiles need no mask (wave-uniform test) ----
    float ps[4][4];
    const bool interior = (kv + 63 <= qw) && ((qw + 15) - kv <= win);
    if (interior) {
#pragma unroll
      for (int n = 0; n < 4; ++n)
#pragma unroll
        for (int r = 0; r < 4; ++r)
          ps[n][r] = exp2f(__builtin_fmaf(s[n][r], SCALE_LOG2E, -FIXSUB));
    } else {
#pragma unroll
      for (int n = 0; n < 4; ++n) {
        const int key = kv + n * 16 + lrow;
#pragma unroll
        for (int r = 0; r < 4; ++r) {
          const int rowq = qw + kg * 4 + r;
          const bool ok = (key <= rowq) && (rowq - key <= win);
          ps[n][r] = ok ? exp2f(__builtin_fmaf(s[n][r], SCALE_LOG2E, -FIXSUB)) : 0.0f;
        }
      }
    }
#pragma unroll
    for (int r = 0; r < 4; ++r)
      lsum[r] += (ps[0][r] + ps[1][r]) + (ps[2][r] + ps[3][r]);
    // ---- P (bf16) -> swizzled per-wave LDS: D-frag -> A-frag layout ----
#pragma unroll
    for (int n = 0; n < 4; ++n)
#pragma unroll
      for (int r = 0; r < 4; ++r) {
        const int rp = kg * 4 + r;
        int bofs = rp * 128 + (n * 16 + lrow) * 2;
        bofs ^= (rp & 7) << 4;
        *reinterpret_cast<u16*>(reinterpret_cast<char*>(Pw) + bofs) = f2bf(ps[n][r]);
      }
    asm volatile("s_waitcnt lgkmcnt(0)" ::: "memory");
    __builtin_amdgcn_s_barrier();  // b2: QK reads of Kl[cur] done before next issueK
    asm volatile("" ::: "memory");
    // ---- O += P V ----
    bf16x8_t ap[2];
#pragma unroll
    for (int k2 = 0; k2 < 2; ++k2) {
      int bofs = lrow * 128 + k2 * 64 + kg * 16;
      bofs ^= (lrow & 7) << 4;
      ap[k2] = *reinterpret_cast<const bf16x8_t*>(reinterpret_cast<const char*>(Pw) + bofs);
    }
    const u16* Vb = &Vl[cur][0];
#pragma unroll
    for (int k2 = 0; k2 < 2; ++k2)
#pragma unroll
      for (int dn = 0; dn < 8; ++dn) {
        const int row = dn * 16 + lrow;
        bf16x8_t bv = *reinterpret_cast<const bf16x8_t*>(
            Vb + row * 64 + (((k2 << 2) | kg) ^ (row & 7)) * 8);
        accv[dn] = MFMA16(ap[k2], bv, accv[dn]);
      }
  }
  // ---- deferred row-sum reduce (within each 16-lane lrow group) ----
#pragma unroll
  for (int off = 1; off < 16; off <<= 1)
#pragma unroll
    for (int r = 0; r < 4; ++r) lsum[r] += __shfl_xor(lsum[r], off, 64);
  float inv[4];
#pragma unroll
  for (int r = 0; r < 4; ++r) inv[r] = 1.0f / lsum[r];
#pragma unroll
  for (int dn = 0; dn < 8; ++dn)
#pragma unroll
    for (int r = 0; r < 4; ++r) {
      const int rowg = b * TSEQ + qw + kg * 4 + r;
      const int col = h * HD + dn * 16 + lrow;
      yh[(size_t)rowg * HIDDEN + col] = f2bf(accv[dn][r] * inv[r]);
    }
}

extern "C" void kernel_launch(void* const* d_in, const int* in_sizes, int n_in, void* d_out,
                              int out_size, void* d_ws, size_t ws_size, hipStream_t stream) {
  const float* x = (const float*)d_in[0];
  const float* cosp = (const float*)d_in[1];
  const float* sinp = (const float*)d_in[2];
  const float* Wq = (const float*)d_in[3];
  const float* Wk = (const float*)d_in[4];
  const float* Wv = (const float*)d_in[5];
  const float* Wp = (const float*)d_in[6];
  const int* winp = (const int*)d_in[7];

  char* ws = (char*)d_ws;
  size_t off = 0;
  auto alloc = [&](size_t bytes) {
    char* p = ws + off;
    off += (bytes + 255) & ~(size_t)255;
    return p;
  };
  u16* xb = (u16*)alloc((size_t)NROWS * HIDDEN * 2);
  u16* wqb = (u16*)alloc((size_t)HIDDEN * HIDDEN * 2);
  u16* wkb = (u16*)alloc((size_t)HIDDEN * HIDDEN * 2);
  u16* wvb = (u16*)alloc((size_t)HIDDEN * HIDDEN * 2);
  u16* wpb = (u16*)alloc((size_t)HIDDEN * HIDDEN * 2);
  u16* qh = (u16*)alloc((size_t)NROWS * HIDDEN * 2);
  u16* kh = (u16*)alloc((size_t)NROWS * HIDDEN * 2);
  u16* vt = (u16*)alloc((size_t)NROWS * HIDDEN * 2);
  u16* yh = (u16*)alloc((size_t)NROWS * HIDDEN * 2);

  const int nx = NROWS * HIDDEN;   // 6291456
  const int nw = HIDDEN * HIDDEN;  // 2359296
  cast_kernel<<<nx / 1024, 256, 0, stream>>>(x, xb, nx);
  cast4_kernel<<<dim3(nw / 1024, 4), 256, 0, stream>>>(Wq, Wk, Wv, Wp, wqb, wkb, wvb, wpb, nw);

  gemm_qkv_kernel<<<dim3(576), 512, 0, stream>>>(xb, wqb, wkb, wvb, cosp, sinp, qh, kh, vt);
  attn_kernel<<<dim3(384), 512, 0, stream>>>(qh, kh, vt, yh, winp);
  gemm_out_kernel<<<dim3(384), 256, 0, stream>>>(yh, wpb, (float*)d_out);
}

// Round 12
// 198.737 us; speedup vs baseline: 1.0253x; 1.0253x over previous
//
#include <hip/hip_runtime.h>
#include <stdint.h>

#define HIDDEN 1536
#define NHEAD 12
#define HD 128
#define TSEQ 2048
#define NROWS 4096
#define KDIM HIDDEN
#define EPS_F 1.1920928955078125e-07f
// (1/sqrt(128)) * log2(e)
#define SCALE_LOG2E 0.12751879110195655f
// fixed softmax shift (log2 domain): scores bounded by sqrt(128)=11.314 (RMS-normed
// q,k => |q||k|<=128 by Cauchy-Schwarz), *log2(e) = 16.32; use 16.6 for bf16 margin.
#define FIXSUB 16.6f

typedef unsigned short u16;
typedef __bf16 bf16x8_t __attribute__((ext_vector_type(8)));
typedef float f32x4_t __attribute__((ext_vector_type(4)));

#define MFMA16(a, b, c) __builtin_amdgcn_mfma_f32_16x16x32_bf16((a), (b), (c), 0, 0, 0)
#define GLL(srcp, dstp) \
  __builtin_amdgcn_global_load_lds((const __attribute__((address_space(1))) void*)(srcp), \
                                   (__attribute__((address_space(3))) void*)(dstp), 16, 0, 0)

__device__ __forceinline__ u16 f2bf(float f) {
  unsigned u = __builtin_bit_cast(unsigned, f);
  u = (u + 0x7fffu + ((u >> 16) & 1u)) >> 16;
  return (u16)u;
}
__device__ __forceinline__ float bfu(u16 v) {
  return __builtin_bit_cast(float, ((unsigned)v) << 16);
}

// ---------------- cast fp32 -> bf16 (vectorized) ----------------
__global__ __launch_bounds__(256) void cast_kernel(const float* __restrict__ in,
                                                   u16* __restrict__ out, int n) {
  int i = (blockIdx.x * 256 + threadIdx.x) * 4;
  if (i >= n) return;
  float4 v = *reinterpret_cast<const float4*>(in + i);
  uint2 pk;
  pk.x = (unsigned)f2bf(v.x) | ((unsigned)f2bf(v.y) << 16);
  pk.y = (unsigned)f2bf(v.z) | ((unsigned)f2bf(v.w) << 16);
  *reinterpret_cast<uint2*>(out + i) = pk;
}

// 4 equal-size weight casts in one launch (blockIdx.y selects)
__global__ __launch_bounds__(256) void cast4_kernel(
    const float* __restrict__ a, const float* __restrict__ b, const float* __restrict__ c,
    const float* __restrict__ d, u16* __restrict__ oa, u16* __restrict__ ob,
    u16* __restrict__ oc, u16* __restrict__ od, int n) {
  const float* in;
  u16* out;
  switch (blockIdx.y) {
    case 0: in = a; out = oa; break;
    case 1: in = b; out = ob; break;
    case 2: in = c; out = oc; break;
    default: in = d; out = od; break;
  }
  int i = (blockIdx.x * 256 + threadIdx.x) * 4;
  if (i >= n) return;
  float4 v = *reinterpret_cast<const float4*>(in + i);
  uint2 pk;
  pk.x = (unsigned)f2bf(v.x) | ((unsigned)f2bf(v.y) << 16);
  pk.y = (unsigned)f2bf(v.z) | ((unsigned)f2bf(v.w) << 16);
  *reinterpret_cast<uint2*>(out + i) = pk;
}

// ---------------- QKV: 256x128 2-barrier GEMM + fused RoPE/RMS epilogue ----------------
// BM=256, BN=128(=HD), BK=64; 512 threads = 8 waves (4M x 2N), 64x64 out/wave.
// SAME loop topology as the proven R8 mainloop (issue-next | counted vmcnt(6) |
// barrier | ds_read+MFMA | lgkm | barrier) -- the 256-row tile halves barrier/stage
// events per MFMA at unchanged 8 waves/CU (96KB LDS -> 1 block/CU).
// LDS: buf b at b*24576 u16: A [0,16384) = 256x64, B [16384,24576) = 128x64;
// XOR-swizzled via pre-swizzled global source + matching XOR on ds_read.
__global__ __launch_bounds__(512, 2) void gemm_qkv_kernel(
    const u16* __restrict__ xb, const u16* __restrict__ wq, const u16* __restrict__ wk,
    const u16* __restrict__ wv, const float* __restrict__ cosp, const float* __restrict__ sinp,
    u16* __restrict__ qh, u16* __restrict__ kh, u16* __restrict__ vt) {
  __shared__ __align__(16) u16 lds[49152];  // 96 KiB
  const int tid = threadIdx.x;
  const int bid = blockIdx.x;              // 576 = 8 XCD x 72
  const int xcd = bid & 7, cc = bid >> 3;  // 0..71
  const int m = xcd * 2 + (cc & 1);        // 0..15 (m-pair per XCD: A-band L2-hot)
  const int nz = cc >> 1;                  // 0..35
  const int z = nz / 12, n = nz % 12;      // weight select / head
  const int M0 = m * 256, N0 = n * 128;
  const u16* W = (z == 0) ? wq : (z == 1) ? wk : wv;
  const int w = tid >> 6, l = tid & 63;
  const int lrow = l & 15, kg = l >> 4;
  const int wm = w >> 1, wn = w & 1;  // 4 M-waves x 2 N-waves
  // ---- staging: A = 2048 chunks (4 passes), B = 1024 chunks (2 passes); 6 GLL/thread
  const int srow = tid >> 3;  // 0..63
  const unsigned jsw = (unsigned)(((tid & 7) ^ (srow & 7)) * 8);  // pre-swizzled col-chunk
  unsigned offA = (unsigned)((M0 + srow) * KDIM) + jsw;
  unsigned offB = (unsigned)((N0 + srow) * KDIM) + jsw;
  const size_t R64 = (size_t)64 * KDIM;
  auto issue = [&](int buf) {
    u16* da = lds + buf * 24576 + w * 512;
    u16* db = lds + buf * 24576 + 16384 + w * 512;
    GLL(xb + offA, da);
    GLL(xb + offA + R64, da + 4096);
    GLL(xb + offA + 2 * R64, da + 8192);
    GLL(xb + offA + 3 * R64, da + 12288);
    GLL(W + offB, db);
    GLL(W + offB + R64, db + 4096);
    offA += 64;
    offB += 64;
  };
  issue(0);
  f32x4_t acc[4][4] = {};
  const int NT = KDIM / 64;  // 24
#pragma unroll 1
  for (int kt = 0; kt < NT; ++kt) {
    const int cur = kt & 1;
    if (kt + 1 < NT) {
      issue(cur ^ 1);
      asm volatile("s_waitcnt vmcnt(6)" ::: "memory");  // current buffer's 6 loads done
    } else {
      asm volatile("s_waitcnt vmcnt(0)" ::: "memory");
    }
    __builtin_amdgcn_s_barrier();
    asm volatile("" ::: "memory");
    const u16* Ab = lds + cur * 24576;
    const u16* Bb = Ab + 16384;
#pragma unroll
    for (int s = 0; s < 2; ++s) {  // two K=32 sub-steps
      bf16x8_t af[4], bf_[4];
#pragma unroll
      for (int mi = 0; mi < 4; ++mi) {
        const int row = wm * 64 + mi * 16 + lrow;
        af[mi] = *reinterpret_cast<const bf16x8_t*>(Ab + row * 64 +
                                                    (((s << 2) | kg) ^ (row & 7)) * 8);
      }
#pragma unroll
      for (int ni = 0; ni < 4; ++ni) {
        const int row = wn * 64 + ni * 16 + lrow;
        bf_[ni] = *reinterpret_cast<const bf16x8_t*>(Bb + row * 64 +
                                                     (((s << 2) | kg) ^ (row & 7)) * 8);
      }
#pragma unroll
      for (int mi = 0; mi < 4; ++mi)
#pragma unroll
        for (int ni = 0; ni < 4; ++ni)
          acc[mi][ni] = MFMA16(af[mi], bf_[ni], acc[mi][ni]);
    }
    asm volatile("s_waitcnt lgkmcnt(0)" ::: "memory");
    __builtin_amdgcn_s_barrier();
    asm volatile("" ::: "memory");
  }
  // ---- epilogue (R10-verified): stage C bf16 swizzled; rope/rms (z<2) or transpose (z=2)
  char* cs = reinterpret_cast<char*>(lds);
  const int bb = M0 >> 11;  // batch (2048 % 256 == 0: tile never straddles)
  const int t0 = M0 & (TSEQ - 1);
  const size_t bhn = (size_t)(bb * NHEAD + n);
  if (z == 2) {
    // [d(128)][t(256)] rows of 512B, XOR (d&7) on 16B-chunk index
#pragma unroll
    for (int mf = 0; mf < 4; ++mf)
#pragma unroll
      for (int nf = 0; nf < 4; ++nf)
#pragma unroll
        for (int r = 0; r < 4; ++r) {
          const int trow = wm * 64 + mf * 16 + kg * 4 + r;
          const int d = wn * 64 + nf * 16 + lrow;
          const int bofs = (d * 512 + trow * 2) ^ ((d & 7) << 4);
          *reinterpret_cast<u16*>(cs + bofs) = f2bf(acc[mf][nf][r]);
        }
    __syncthreads();
    const int d = tid >> 2, tq = tid & 3;  // 128 d x 4 t-quarters
    u16* dst = vt + (bhn * HD + d) * TSEQ + t0 + tq * 64;
    const char* rb = cs + d * 512 + tq * 128;
#pragma unroll
    for (int j = 0; j < 8; ++j) {
      uint4 v = *reinterpret_cast<const uint4*>(rb + ((j ^ (d & 7)) * 16));
      *reinterpret_cast<uint4*>(dst + j * 8) = v;
    }
  } else {
    // [t(256)][d(128)] rows of 256B, XOR (t&7) on 16B-chunk index
#pragma unroll
    for (int mf = 0; mf < 4; ++mf)
#pragma unroll
      for (int nf = 0; nf < 4; ++nf)
#pragma unroll
        for (int r = 0; r < 4; ++r) {
          const int trow = wm * 64 + mf * 16 + kg * 4 + r;
          const int d = wn * 64 + nf * 16 + lrow;
          const int bofs = (trow * 256 + d * 2) ^ ((trow & 7) << 4);
          *reinterpret_cast<u16*>(cs + bofs) = f2bf(acc[mf][nf][r]);
        }
    __syncthreads();
    const int rr = tid >> 1, hh = tid & 1;  // 256 rows x 2 d-halves
    const int t = t0 + rr;
    const float* cosb = cosp + t * 64;
    const float* sinb = sinp + t * 64;
    const char* base = cs + rr * 256;
    float ss = 0.0f;
    unsigned pk[32];  // 64 rope'd values packed bf16x2
#pragma unroll
    for (int j = 0; j < 8; ++j) {
      const int jp = (j ^ (rr & 7)) * 16;
      uint4 vo = *reinterpret_cast<const uint4*>(base + hh * 128 + jp);        // own half
      uint4 vx = *reinterpret_cast<const uint4*>(base + (hh ^ 1) * 128 + jp);  // other half
      const unsigned vo32[4] = {vo.x, vo.y, vo.z, vo.w};
      const unsigned vx32[4] = {vx.x, vx.y, vx.z, vx.w};
      const float* cj = cosb + j * 8;
      const float* sj = sinb + j * 8;
#pragma unroll
      for (int q2 = 0; q2 < 4; ++q2) {
        float o0 = bfu((u16)(vo32[q2] & 0xffffu)), o1 = bfu((u16)(vo32[q2] >> 16));
        float x0 = bfu((u16)(vx32[q2] & 0xffffu)), x1 = bfu((u16)(vx32[q2] >> 16));
        float cc0 = cj[q2 * 2], cc1 = cj[q2 * 2 + 1];
        float s0 = sj[q2 * 2], s1 = sj[q2 * 2 + 1];
        // hh=0: y = x1*cos + x2*sin ; hh=1: y = x2*cos - x1*sin
        float y0 = hh ? __builtin_fmaf(o0, cc0, -x0 * s0) : __builtin_fmaf(o0, cc0, x0 * s0);
        float y1 = hh ? __builtin_fmaf(o1, cc1, -x1 * s1) : __builtin_fmaf(o1, cc1, x1 * s1);
        ss = __builtin_fmaf(y0, y0, __builtin_fmaf(y1, y1, ss));
        pk[j * 4 + q2] = (unsigned)f2bf(y0) | ((unsigned)f2bf(y1) << 16);
      }
    }
    ss += __shfl_xor(ss, 1, 64);  // partner thread holds the other half of this row
    const float rinv = rsqrtf(ss * (1.0f / 128.0f) + EPS_F);
    u16* dst = ((z == 0) ? qh : kh) + (bhn * TSEQ + t) * HD + hh * 64;
#pragma unroll
    for (int j = 0; j < 8; ++j) {
      unsigned o[4];
#pragma unroll
      for (int q2 = 0; q2 < 4; ++q2) {
        float y0 = bfu((u16)(pk[j * 4 + q2] & 0xffffu)) * rinv;
        float y1 = bfu((u16)(pk[j * 4 + q2] >> 16)) * rinv;
        o[q2] = (unsigned)f2bf(y0) | ((unsigned)f2bf(y1) << 16);
      }
      uint4 v;
      v.x = o[0]; v.y = o[1]; v.z = o[2]; v.w = o[3];
      *reinterpret_cast<uint4*>(dst + j * 8) = v;
    }
  }
}

// ---------------- shared NT-GEMM mainloop, BK=64 (R8-proven; used by gemm_out) ----------------
__device__ __forceinline__ void gemm_mainloop64(const u16* __restrict__ A,
                                                const u16* __restrict__ W, int M0, int N0,
                                                u16* lds, f32x4_t acc[4][4], int tid) {
  const int w = tid >> 6, l = tid & 63;
  const int lrow = l & 15, kg = l >> 4;
  const int wr = (w >> 1) * 64, wc = (w & 1) * 64;
  const int row0 = tid >> 3, j0 = tid & 7;
  const unsigned jsw = (unsigned)((j0 ^ (row0 & 7)) * 8);
  unsigned offA = (unsigned)((M0 + row0) * KDIM) + jsw;
  unsigned offW = (unsigned)((N0 + row0) * KDIM) + jsw;
  const u16* A1 = A + 32 * KDIM; const u16* A2 = A + 64 * KDIM; const u16* A3 = A + 96 * KDIM;
  const u16* W1 = W + 32 * KDIM; const u16* W2 = W + 64 * KDIM; const u16* W3 = W + 96 * KDIM;
  auto issue = [&](int buf) {
    u16* da = lds + buf * 8192 + w * 512;
    u16* dw = lds + 16384 + buf * 8192 + w * 512;
    GLL(A + offA, da);          GLL(A1 + offA, da + 2048);
    GLL(A2 + offA, da + 4096);  GLL(A3 + offA, da + 6144);
    GLL(W + offW, dw);          GLL(W1 + offW, dw + 2048);
    GLL(W2 + offW, dw + 4096);  GLL(W3 + offW, dw + 6144);
    offA += 64; offW += 64;
  };
  issue(0);
  const int NT = KDIM / 64;  // 24
#pragma unroll 1
  for (int kt = 0; kt < NT; ++kt) {
    const int cur = kt & 1;
    if (kt + 1 < NT) {
      issue(cur ^ 1);
      asm volatile("s_waitcnt vmcnt(8)" ::: "memory");
    } else {
      asm volatile("s_waitcnt vmcnt(0)" ::: "memory");
    }
    __builtin_amdgcn_s_barrier();
    asm volatile("" ::: "memory");
    const u16* Ab = lds + cur * 8192;
    const u16* Wb = lds + 16384 + cur * 8192;
#pragma unroll
    for (int s = 0; s < 2; ++s) {
      bf16x8_t af[4], bf_[4];
#pragma unroll
      for (int mi = 0; mi < 4; ++mi) {
        const int row = wr + mi * 16 + lrow;
        af[mi] = *reinterpret_cast<const bf16x8_t*>(Ab + row * 64 +
                                                    (((s << 2) | kg) ^ (row & 7)) * 8);
      }
#pragma unroll
      for (int ni = 0; ni < 4; ++ni) {
        const int row = wc + ni * 16 + lrow;
        bf_[ni] = *reinterpret_cast<const bf16x8_t*>(Wb + row * 64 +
                                                     (((s << 2) | kg) ^ (row & 7)) * 8);
      }
#pragma unroll
      for (int mi = 0; mi < 4; ++mi)
#pragma unroll
        for (int ni = 0; ni < 4; ++ni)
          acc[mi][ni] = MFMA16(af[mi], bf_[ni], acc[mi][ni]);
    }
    asm volatile("s_waitcnt lgkmcnt(0)" ::: "memory");
    __builtin_amdgcn_s_barrier();
    asm volatile("" ::: "memory");
  }
}

// ---------------- output projection (flattened grid, XCD-chunked; R8-proven) ----------------
__global__ __launch_bounds__(256) void gemm_out_kernel(const u16* __restrict__ yh,
                                                       const u16* __restrict__ wp,
                                                       float* __restrict__ out) {
  __shared__ __align__(16) u16 lds[32768];
  const int tid = threadIdx.x;
  const int wgid = blockIdx.x;
  const int xcd = wgid & 7, c = wgid >> 3;
  const int m = ((xcd & 3) << 3) + (c & 7);
  const int n = ((xcd >> 2) * 6) + (c >> 3);
  const int M0 = m * 128, N0 = n * 128;
  f32x4_t acc[4][4] = {};
  gemm_mainloop64(yh, wp, M0, N0, lds, acc, tid);
  const int w = tid >> 6, l = tid & 63;
  const int lrow = l & 15, kg = l >> 4;
  const int wr = (w >> 1) * 64, wc = (w & 1) * 64;
#pragma unroll
  for (int mi = 0; mi < 4; ++mi)
#pragma unroll
    for (int ni = 0; ni < 4; ++ni)
#pragma unroll
      for (int r = 0; r < 4; ++r) {
        const int grow = M0 + wr + mi * 16 + kg * 4 + r;
        const int gcol = N0 + wc + ni * 16 + lrow;
        out[(size_t)grow * HIDDEN + gcol] = acc[mi][ni][r];
      }
}

// ---------------- flash attention: 2-barrier pipeline, dbuf K AND V (R9-proven) ----------------
__global__ __launch_bounds__(512, 4) void attn_kernel(const u16* __restrict__ qh,
                                                      const u16* __restrict__ kh,
                                                      const u16* __restrict__ vt,
                                                      u16* __restrict__ yh,
                                                      const int* __restrict__ winp) {
  __shared__ __align__(16) u16 Kl[2][8192];  // [buf][64 keys x 128 d], swizzled
  __shared__ __align__(16) u16 Vl[2][8192];  // [buf][128 d x 64 t], swizzled
  __shared__ __align__(16) u16 Pl[8][1024];  // per-wave 16x64 P, swizzled
  const int tid = threadIdx.x, w = tid >> 6, l = tid & 63;
  const int lrow = l & 15, kg = l >> 4;
  const int bid = blockIdx.x;  // 384 = 8 XCDs x 48
  const int swz = (bid & 7) * 48 + (bid >> 3);
  const int qb = swz & 15;  // q-block (128 rows) within (b,h)
  const int bh = swz >> 4;  // 0..23
  const int h = bh % NHEAD, b = bh / NHEAD;
  const int win = winp[0];
  const u16* Q = qh + (size_t)bh * TSEQ * HD;
  const u16* K = kh + (size_t)bh * TSEQ * HD;
  const u16* V = vt + (size_t)bh * HD * TSEQ;
  const int qw = qb * 128 + w * 16;  // this wave's 16 q-rows
  bf16x8_t aq[4];
#pragma unroll
  for (int ks = 0; ks < 4; ++ks)
    aq[ks] = *reinterpret_cast<const bf16x8_t*>(Q + (qw + lrow) * HD + ks * 32 + kg * 8);
  float lsum[4] = {0.f, 0.f, 0.f, 0.f};  // per-lane partial row sums (reduced post-loop)
  f32x4_t accv[8] = {};
  int lo = qb * 128 - win;
  if (lo < 0) lo = 0;
  lo &= ~63;
  const int last = qb * 128 + 64;  // last KV tile start (diagonal tile)

  u16* Pw = &Pl[w][0];

  auto stage_k = [&](int kv, int buf) {
#pragma unroll
    for (int i = 0; i < 2; ++i) {
      const int c = i * 512 + w * 64 + l;
      const int row = c >> 4, j = c & 15;
      const u16* src = K + (size_t)(kv + row) * HD + ((j ^ (row & 7)) * 8);
      GLL(src, &Kl[buf][0] + i * 4096 + w * 512);
    }
  };
  auto stage_v = [&](int kv, int buf) {
#pragma unroll
    for (int i = 0; i < 2; ++i) {
      const int c = i * 512 + w * 64 + l;
      const int row = c >> 3, j = c & 7;
      const u16* src = V + (size_t)row * TSEQ + kv + ((j ^ (row & 7)) * 8);
      GLL(src, &Vl[buf][0] + i * 4096 + w * 512);
    }
  };

  stage_k(lo, 0);
  stage_v(lo, 0);  // prologue: 4 loads in flight
  int it = 0;
  for (int kv = lo; kv <= last; kv += 64, ++it) {
    const int cur = it & 1;
    const int kpre = (kv + 64 <= last) ? kv + 64 : last;  // clamp tail prefetch
    stage_k(kpre, cur ^ 1);                               // +2 -> 6 outstanding
    asm volatile("s_waitcnt vmcnt(2)" ::: "memory");      // K(kv),V(kv) landed
    __builtin_amdgcn_s_barrier();                         // b1
    asm volatile("" ::: "memory");
    stage_v(kpre, cur ^ 1);  // +2 (Vl[cur^1] PV-reads all finished before b1)
    // ---- S = Q K^T (16 x 64) from LDS ----
    const u16* Kb = &Kl[cur][0];
    f32x4_t s[4] = {};
#pragma unroll
    for (int n = 0; n < 4; ++n) {
      const int row = n * 16 + lrow;
#pragma unroll
      for (int ks = 0; ks < 4; ++ks) {
        bf16x8_t bk = *reinterpret_cast<const bf16x8_t*>(
            Kb + row * 128 + (((ks << 2) | kg) ^ (row & 7)) * 8);
        s[n] = MFMA16(aq[ks], bk, s[n]);
      }
    }
    // ---- softmax: interior tiles need no mask (wave-uniform test) ----
    float ps[4][4];
    const bool interior = (kv + 63 <= qw) && ((qw + 15) - kv <= win);
    if (interior) {
#pragma unroll
      for (int n = 0; n < 4; ++n)
#pragma unroll
        for (int r = 0; r < 4; ++r)
          ps[n][r] = exp2f(__builtin_fmaf(s[n][r], SCALE_LOG2E, -FIXSUB));
    } else {
#pragma unroll
      for (int n = 0; n < 4; ++n) {
        const int key = kv + n * 16 + lrow;
#pragma unroll
        for (int r = 0; r < 4; ++r) {
          const int rowq = qw + kg * 4 + r;
          const bool ok = (key <= rowq) && (rowq - key <= win);
          ps[n][r] = ok ? exp2f(__builtin_fmaf(s[n][r], SCALE_LOG2E, -FIXSUB)) : 0.0f;
        }
      }
    }
#pragma unroll
    for (int r = 0; r < 4; ++r)
      lsum[r] += (ps[0][r] + ps[1][r]) + (ps[2][r] + ps[3][r]);
    // ---- P (bf16) -> swizzled per-wave LDS: D-frag -> A-frag layout ----
#pragma unroll
    for (int n = 0; n < 4; ++n)
#pragma unroll
      for (int r = 0; r < 4; ++r) {
        const int rp = kg * 4 + r;
        int bofs = rp * 128 + (n * 16 + lrow) * 2;
        bofs ^= (rp & 7) << 4;
        *reinterpret_cast<u16*>(reinterpret_cast<char*>(Pw) + bofs) = f2bf(ps[n][r]);
      }
    asm volatile("s_waitcnt lgkmcnt(0)" ::: "memory");
    __builtin_amdgcn_s_barrier();  // b2: QK reads of Kl[cur] done before next issueK
    asm volatile("" ::: "memory");
    // ---- O += P V ----
    bf16x8_t ap[2];
#pragma unroll
    for (int k2 = 0; k2 < 2; ++k2) {
      int bofs = lrow * 128 + k2 * 64 + kg * 16;
      bofs ^= (lrow & 7) << 4;
      ap[k2] = *reinterpret_cast<const bf16x8_t*>(reinterpret_cast<const char*>(Pw) + bofs);
    }
    const u16* Vb = &Vl[cur][0];
#pragma unroll
    for (int k2 = 0; k2 < 2; ++k2)
#pragma unroll
      for (int dn = 0; dn < 8; ++dn) {
        const int row = dn * 16 + lrow;
        bf16x8_t bv = *reinterpret_cast<const bf16x8_t*>(
            Vb + row * 64 + (((k2 << 2) | kg) ^ (row & 7)) * 8);
        accv[dn] = MFMA16(ap[k2], bv, accv[dn]);
      }
  }
  // ---- deferred row-sum reduce (within each 16-lane lrow group) ----
#pragma unroll
  for (int off = 1; off < 16; off <<= 1)
#pragma unroll
    for (int r = 0; r < 4; ++r) lsum[r] += __shfl_xor(lsum[r], off, 64);
  float inv[4];
#pragma unroll
  for (int r = 0; r < 4; ++r) inv[r] = 1.0f / lsum[r];
#pragma unroll
  for (int dn = 0; dn < 8; ++dn)
#pragma unroll
    for (int r = 0; r < 4; ++r) {
      const int rowg = b * TSEQ + qw + kg * 4 + r;
      const int col = h * HD + dn * 16 + lrow;
      yh[(size_t)rowg * HIDDEN + col] = f2bf(accv[dn][r] * inv[r]);
    }
}

extern "C" void kernel_launch(void* const* d_in, const int* in_sizes, int n_in, void* d_out,
                              int out_size, void* d_ws, size_t ws_size, hipStream_t stream) {
  const float* x = (const float*)d_in[0];
  const float* cosp = (const float*)d_in[1];
  const float* sinp = (const float*)d_in[2];
  const float* Wq = (const float*)d_in[3];
  const float* Wk = (const float*)d_in[4];
  const float* Wv = (const float*)d_in[5];
  const float* Wp = (const float*)d_in[6];
  const int* winp = (const int*)d_in[7];

  char* ws = (char*)d_ws;
  size_t off = 0;
  auto alloc = [&](size_t bytes) {
    char* p = ws + off;
    off += (bytes + 255) & ~(size_t)255;
    return p;
  };
  u16* xb = (u16*)alloc((size_t)NROWS * HIDDEN * 2);
  u16* wqb = (u16*)alloc((size_t)HIDDEN * HIDDEN * 2);
  u16* wkb = (u16*)alloc((size_t)HIDDEN * HIDDEN * 2);
  u16* wvb = (u16*)alloc((size_t)HIDDEN * HIDDEN * 2);
  u16* wpb = (u16*)alloc((size_t)HIDDEN * HIDDEN * 2);
  u16* qh = (u16*)alloc((size_t)NROWS * HIDDEN * 2);
  u16* kh = (u16*)alloc((size_t)NROWS * HIDDEN * 2);
  u16* vt = (u16*)alloc((size_t)NROWS * HIDDEN * 2);
  u16* yh = (u16*)alloc((size_t)NROWS * HIDDEN * 2);

  const int nx = NROWS * HIDDEN;   // 6291456
  const int nw = HIDDEN * HIDDEN;  // 2359296
  cast_kernel<<<nx / 1024, 256, 0, stream>>>(x, xb, nx);
  cast4_kernel<<<dim3(nw / 1024, 4), 256, 0, stream>>>(Wq, Wk, Wv, Wp, wqb, wkb, wvb, wpb, nw);

  gemm_qkv_kernel<<<dim3(576), 512, 0, stream>>>(xb, wqb, wkb, wvb, cosp, sinp, qh, kh, vt);
  attn_kernel<<<dim3(384), 512, 0, stream>>>(qh, kh, vt, yh, winp);
  gemm_out_kernel<<<dim3(384), 256, 0, stream>>>(yh, wpb, (float*)d_out);
}

// Round 13
// 185.597 us; speedup vs baseline: 1.0979x; 1.0708x over previous
//
#include <hip/hip_runtime.h>
#include <stdint.h>

#define HIDDEN 1536
#define NHEAD 12
#define HD 128
#define TSEQ 2048
#define NROWS 4096
#define KDIM HIDDEN
#define EPS_F 1.1920928955078125e-07f
// (1/sqrt(128)) * log2(e)
#define SCALE_LOG2E 0.12751879110195655f
// fixed softmax shift (log2 domain): scores bounded by sqrt(128)=11.314 (RMS-normed
// q,k => |q||k|<=128 by Cauchy-Schwarz), *log2(e) = 16.32; use 16.6 for bf16 margin.
#define FIXSUB 16.6f

typedef unsigned short u16;
typedef __bf16 bf16x8_t __attribute__((ext_vector_type(8)));
typedef float f32x4_t __attribute__((ext_vector_type(4)));

#define MFMA16(a, b, c) __builtin_amdgcn_mfma_f32_16x16x32_bf16((a), (b), (c), 0, 0, 0)
#define GLL(srcp, dstp) \
  __builtin_amdgcn_global_load_lds((const __attribute__((address_space(1))) void*)(srcp), \
                                   (__attribute__((address_space(3))) void*)(dstp), 16, 0, 0)

__device__ __forceinline__ u16 f2bf(float f) {
  unsigned u = __builtin_bit_cast(unsigned, f);
  u = (u + 0x7fffu + ((u >> 16) & 1u)) >> 16;
  return (u16)u;
}
__device__ __forceinline__ float bfu(u16 v) {
  return __builtin_bit_cast(float, ((unsigned)v) << 16);
}

// ---------------- cast fp32 -> bf16 (vectorized) ----------------
__global__ __launch_bounds__(256) void cast_kernel(const float* __restrict__ in,
                                                   u16* __restrict__ out, int n) {
  int i = (blockIdx.x * 256 + threadIdx.x) * 4;
  if (i >= n) return;
  float4 v = *reinterpret_cast<const float4*>(in + i);
  uint2 pk;
  pk.x = (unsigned)f2bf(v.x) | ((unsigned)f2bf(v.y) << 16);
  pk.y = (unsigned)f2bf(v.z) | ((unsigned)f2bf(v.w) << 16);
  *reinterpret_cast<uint2*>(out + i) = pk;
}

// 4 equal-size weight casts in one launch (blockIdx.y selects)
__global__ __launch_bounds__(256) void cast4_kernel(
    const float* __restrict__ a, const float* __restrict__ b, const float* __restrict__ c,
    const float* __restrict__ d, u16* __restrict__ oa, u16* __restrict__ ob,
    u16* __restrict__ oc, u16* __restrict__ od, int n) {
  const float* in;
  u16* out;
  switch (blockIdx.y) {
    case 0: in = a; out = oa; break;
    case 1: in = b; out = ob; break;
    case 2: in = c; out = oc; break;
    default: in = d; out = od; break;
  }
  int i = (blockIdx.x * 256 + threadIdx.x) * 4;
  if (i >= n) return;
  float4 v = *reinterpret_cast<const float4*>(in + i);
  uint2 pk;
  pk.x = (unsigned)f2bf(v.x) | ((unsigned)f2bf(v.y) << 16);
  pk.y = (unsigned)f2bf(v.z) | ((unsigned)f2bf(v.w) << 16);
  *reinterpret_cast<uint2*>(out + i) = pk;
}

// ---------------- shared NT-GEMM mainloop, BK=64 (R8-proven) ----------------
// 128x128 tile, 4 waves, double-buffered 64KB LDS, counted vmcnt(8) (loads stay
// in flight across barriers). 2 blocks/CU -> cross-block overlap hides the
// barrier drain (removing it regressed: R12). XOR-swizzled LDS via pre-swizzled
// global source + matching XOR on ds_read (conflict-free, 197K cyc measured).
__device__ __forceinline__ void gemm_mainloop64(const u16* __restrict__ A,
                                                const u16* __restrict__ W, int M0, int N0,
                                                u16* lds, f32x4_t acc[4][4], int tid) {
  const int w = tid >> 6, l = tid & 63;
  const int lrow = l & 15, kg = l >> 4;
  const int wr = (w >> 1) * 64, wc = (w & 1) * 64;
  const int row0 = tid >> 3, j0 = tid & 7;
  const unsigned jsw = (unsigned)((j0 ^ (row0 & 7)) * 8);
  unsigned offA = (unsigned)((M0 + row0) * KDIM) + jsw;
  unsigned offW = (unsigned)((N0 + row0) * KDIM) + jsw;
  const u16* A1 = A + 32 * KDIM; const u16* A2 = A + 64 * KDIM; const u16* A3 = A + 96 * KDIM;
  const u16* W1 = W + 32 * KDIM; const u16* W2 = W + 64 * KDIM; const u16* W3 = W + 96 * KDIM;
  auto issue = [&](int buf) {
    u16* da = lds + buf * 8192 + w * 512;
    u16* dw = lds + 16384 + buf * 8192 + w * 512;
    GLL(A + offA, da);          GLL(A1 + offA, da + 2048);
    GLL(A2 + offA, da + 4096);  GLL(A3 + offA, da + 6144);
    GLL(W + offW, dw);          GLL(W1 + offW, dw + 2048);
    GLL(W2 + offW, dw + 4096);  GLL(W3 + offW, dw + 6144);
    offA += 64; offW += 64;
  };
  issue(0);
  const int NT = KDIM / 64;  // 24
#pragma unroll 1
  for (int kt = 0; kt < NT; ++kt) {
    const int cur = kt & 1;
    if (kt + 1 < NT) {
      issue(cur ^ 1);
      asm volatile("s_waitcnt vmcnt(8)" ::: "memory");
    } else {
      asm volatile("s_waitcnt vmcnt(0)" ::: "memory");
    }
    __builtin_amdgcn_s_barrier();
    asm volatile("" ::: "memory");
    const u16* Ab = lds + cur * 8192;
    const u16* Wb = lds + 16384 + cur * 8192;
#pragma unroll
    for (int s = 0; s < 2; ++s) {
      bf16x8_t af[4], bf_[4];
#pragma unroll
      for (int mi = 0; mi < 4; ++mi) {
        const int row = wr + mi * 16 + lrow;
        af[mi] = *reinterpret_cast<const bf16x8_t*>(Ab + row * 64 +
                                                    (((s << 2) | kg) ^ (row & 7)) * 8);
      }
#pragma unroll
      for (int ni = 0; ni < 4; ++ni) {
        const int row = wc + ni * 16 + lrow;
        bf_[ni] = *reinterpret_cast<const bf16x8_t*>(Wb + row * 64 +
                                                     (((s << 2) | kg) ^ (row & 7)) * 8);
      }
#pragma unroll
      for (int mi = 0; mi < 4; ++mi)
#pragma unroll
        for (int ni = 0; ni < 4; ++ni)
          acc[mi][ni] = MFMA16(af[mi], bf_[ni], acc[mi][ni]);
    }
    asm volatile("s_waitcnt lgkmcnt(0)" ::: "memory");
    __builtin_amdgcn_s_barrier();
    asm volatile("" ::: "memory");
  }
}

// ---------------- QKV projection + fused RoPE/RMSNorm epilogue (per-z blocks) ----------------
// Grid 1152 flattened, XCD-chunked (8 XCDs x [8m x 18nz]); A-band L2-resident.
// Epilogue: stage C bf16 swizzled into first 16KB of LDS, then
// z=0/1: in-block RoPE+RMSNorm -> qh/kh; z=2: transpose -> vt, 16B stores.
__global__ __launch_bounds__(256) void gemm_qkv_kernel(
    const u16* __restrict__ xb, const u16* __restrict__ wq, const u16* __restrict__ wk,
    const u16* __restrict__ wv, const float* __restrict__ cosp, const float* __restrict__ sinp,
    u16* __restrict__ qh, u16* __restrict__ kh, u16* __restrict__ vt) {
  __shared__ __align__(16) u16 lds[32768];
  const int tid = threadIdx.x;
  const int wgid = blockIdx.x;
  const int xcd = wgid & 7, c = wgid >> 3;      // c in [0,144)
  const int m = ((xcd & 3) << 3) + (c & 7);     // 0..31
  const int nz = ((xcd >> 2) * 18) + (c >> 3);  // 0..35
  const int z = nz / 12, n = nz % 12;
  const int M0 = m * 128, N0 = n * 128;
  const u16* W = (z == 0) ? wq : (z == 1) ? wk : wv;
  f32x4_t acc[4][4] = {};
  gemm_mainloop64(xb, W, M0, N0, lds, acc, tid);
  const int w = tid >> 6, l = tid & 63;
  const int lrow = l & 15, kg = l >> 4;
  const int wr = (w >> 1) * 64, wc = (w & 1) * 64;
  char* cs = reinterpret_cast<char*>(lds);
  if (z == 2) {
#pragma unroll
    for (int mi = 0; mi < 4; ++mi)
#pragma unroll
      for (int ni = 0; ni < 4; ++ni)
#pragma unroll
        for (int r = 0; r < 4; ++r) {
          const int t_l = wr + mi * 16 + kg * 4 + r;
          const int d = wc + ni * 16 + lrow;
          const int bofs = (d * 256 + t_l * 2) ^ ((d & 7) << 4);
          *reinterpret_cast<u16*>(cs + bofs) = f2bf(acc[mi][ni][r]);
        }
  } else {
#pragma unroll
    for (int mi = 0; mi < 4; ++mi)
#pragma unroll
      for (int ni = 0; ni < 4; ++ni)
#pragma unroll
        for (int r = 0; r < 4; ++r) {
          const int t_l = wr + mi * 16 + kg * 4 + r;
          const int d = wc + ni * 16 + lrow;
          const int bofs = (t_l * 256 + d * 2) ^ ((t_l & 7) << 4);
          *reinterpret_cast<u16*>(cs + bofs) = f2bf(acc[mi][ni][r]);
        }
  }
  __syncthreads();
  const int rr = tid >> 1, hh = tid & 1;
  const int bb = M0 >> 11;
  const int t0 = M0 & (TSEQ - 1);
  const size_t bhn = (size_t)(bb * NHEAD + n);
  if (z == 2) {
    u16* dst = vt + (bhn * HD + rr) * TSEQ + t0 + hh * 64;
    const char* base = cs + rr * 256 + hh * 128;
#pragma unroll
    for (int j = 0; j < 8; ++j) {
      uint4 v = *reinterpret_cast<const uint4*>(base + ((j ^ (rr & 7)) * 16));
      *reinterpret_cast<uint4*>(dst + j * 8) = v;
    }
  } else {
    const int t = t0 + rr;
    const float* cosb = cosp + t * 64;
    const float* sinb = sinp + t * 64;
    const char* base = cs + rr * 256;
    float ss = 0.0f;
    unsigned pk[32];
#pragma unroll
    for (int j = 0; j < 8; ++j) {
      const int jp = (j ^ (rr & 7)) * 16;
      uint4 vo = *reinterpret_cast<const uint4*>(base + hh * 128 + jp);
      uint4 vx = *reinterpret_cast<const uint4*>(base + (hh ^ 1) * 128 + jp);
      const unsigned vo32[4] = {vo.x, vo.y, vo.z, vo.w};
      const unsigned vx32[4] = {vx.x, vx.y, vx.z, vx.w};
      const float* cj = cosb + j * 8;
      const float* sj = sinb + j * 8;
#pragma unroll
      for (int q2 = 0; q2 < 4; ++q2) {
        float o0 = bfu((u16)(vo32[q2] & 0xffffu)), o1 = bfu((u16)(vo32[q2] >> 16));
        float x0 = bfu((u16)(vx32[q2] & 0xffffu)), x1 = bfu((u16)(vx32[q2] >> 16));
        float cc0 = cj[q2 * 2], cc1 = cj[q2 * 2 + 1];
        float s0 = sj[q2 * 2], s1 = sj[q2 * 2 + 1];
        float y0 = hh ? __builtin_fmaf(o0, cc0, -x0 * s0) : __builtin_fmaf(o0, cc0, x0 * s0);
        float y1 = hh ? __builtin_fmaf(o1, cc1, -x1 * s1) : __builtin_fmaf(o1, cc1, x1 * s1);
        ss = __builtin_fmaf(y0, y0, __builtin_fmaf(y1, y1, ss));
        pk[j * 4 + q2] = (unsigned)f2bf(y0) | ((unsigned)f2bf(y1) << 16);
      }
    }
    ss += __shfl_xor(ss, 1, 64);
    const float rinv = rsqrtf(ss * (1.0f / 128.0f) + EPS_F);
    u16* dst = ((z == 0) ? qh : kh) + (bhn * TSEQ + t) * HD + hh * 64;
#pragma unroll
    for (int j = 0; j < 8; ++j) {
      unsigned o[4];
#pragma unroll
      for (int q2 = 0; q2 < 4; ++q2) {
        float y0 = bfu((u16)(pk[j * 4 + q2] & 0xffffu)) * rinv;
        float y1 = bfu((u16)(pk[j * 4 + q2] >> 16)) * rinv;
        o[q2] = (unsigned)f2bf(y0) | ((unsigned)f2bf(y1) << 16);
      }
      uint4 v;
      v.x = o[0]; v.y = o[1]; v.z = o[2]; v.w = o[3];
      *reinterpret_cast<uint4*>(dst + j * 8) = v;
    }
  }
}

// ---------------- output projection (flattened grid, XCD-chunked; R8-proven) ----------------
__global__ __launch_bounds__(256) void gemm_out_kernel(const u16* __restrict__ yh,
                                                       const u16* __restrict__ wp,
                                                       float* __restrict__ out) {
  __shared__ __align__(16) u16 lds[32768];
  const int tid = threadIdx.x;
  const int wgid = blockIdx.x;
  const int xcd = wgid & 7, c = wgid >> 3;
  const int m = ((xcd & 3) << 3) + (c & 7);
  const int n = ((xcd >> 2) * 6) + (c >> 3);
  const int M0 = m * 128, N0 = n * 128;
  f32x4_t acc[4][4] = {};
  gemm_mainloop64(yh, wp, M0, N0, lds, acc, tid);
  const int w = tid >> 6, l = tid & 63;
  const int lrow = l & 15, kg = l >> 4;
  const int wr = (w >> 1) * 64, wc = (w & 1) * 64;
#pragma unroll
  for (int mi = 0; mi < 4; ++mi)
#pragma unroll
    for (int ni = 0; ni < 4; ++ni)
#pragma unroll
      for (int r = 0; r < 4; ++r) {
        const int grow = M0 + wr + mi * 16 + kg * 4 + r;
        const int gcol = N0 + wc + ni * 16 + lrow;
        out[(size_t)grow * HIDDEN + gcol] = acc[mi][ni][r];
      }
}

// ---------------- flash attention: 2-barrier pipeline, dbuf K AND V (R9-proven) ----------------
// 8 waves x 16 q-rows = 128 q-rows/block. Per iter: issueK(next) | vmcnt(2) | b1 |
// issueV(next) | QK | softmax | Pwrite+lgkm | b2 | PV. Interior tiles skip mask
// VALU (wave-uniform test); row-sum reduce deferred to one post-loop shuffle.
__global__ __launch_bounds__(512, 4) void attn_kernel(const u16* __restrict__ qh,
                                                      const u16* __restrict__ kh,
                                                      const u16* __restrict__ vt,
                                                      u16* __restrict__ yh,
                                                      const int* __restrict__ winp) {
  __shared__ __align__(16) u16 Kl[2][8192];  // [buf][64 keys x 128 d], swizzled
  __shared__ __align__(16) u16 Vl[2][8192];  // [buf][128 d x 64 t], swizzled
  __shared__ __align__(16) u16 Pl[8][1024];  // per-wave 16x64 P, swizzled
  const int tid = threadIdx.x, w = tid >> 6, l = tid & 63;
  const int lrow = l & 15, kg = l >> 4;
  const int bid = blockIdx.x;  // 384 = 8 XCDs x 48
  const int swz = (bid & 7) * 48 + (bid >> 3);
  const int qb = swz & 15;  // q-block (128 rows) within (b,h)
  const int bh = swz >> 4;  // 0..23
  const int h = bh % NHEAD, b = bh / NHEAD;
  const int win = winp[0];
  const u16* Q = qh + (size_t)bh * TSEQ * HD;
  const u16* K = kh + (size_t)bh * TSEQ * HD;
  const u16* V = vt + (size_t)bh * HD * TSEQ;
  const int qw = qb * 128 + w * 16;  // this wave's 16 q-rows
  bf16x8_t aq[4];
#pragma unroll
  for (int ks = 0; ks < 4; ++ks)
    aq[ks] = *reinterpret_cast<const bf16x8_t*>(Q + (qw + lrow) * HD + ks * 32 + kg * 8);
  float lsum[4] = {0.f, 0.f, 0.f, 0.f};  // per-lane partial row sums (reduced post-loop)
  f32x4_t accv[8] = {};
  int lo = qb * 128 - win;
  if (lo < 0) lo = 0;
  lo &= ~63;
  const int last = qb * 128 + 64;  // last KV tile start (diagonal tile)

  u16* Pw = &Pl[w][0];

  auto stage_k = [&](int kv, int buf) {
#pragma unroll
    for (int i = 0; i < 2; ++i) {
      const int c = i * 512 + w * 64 + l;
      const int row = c >> 4, j = c & 15;
      const u16* src = K + (size_t)(kv + row) * HD + ((j ^ (row & 7)) * 8);
      GLL(src, &Kl[buf][0] + i * 4096 + w * 512);
    }
  };
  auto stage_v = [&](int kv, int buf) {
#pragma unroll
    for (int i = 0; i < 2; ++i) {
      const int c = i * 512 + w * 64 + l;
      const int row = c >> 3, j = c & 7;
      const u16* src = V + (size_t)row * TSEQ + kv + ((j ^ (row & 7)) * 8);
      GLL(src, &Vl[buf][0] + i * 4096 + w * 512);
    }
  };

  stage_k(lo, 0);
  stage_v(lo, 0);  // prologue: 4 loads in flight
  int it = 0;
  for (int kv = lo; kv <= last; kv += 64, ++it) {
    const int cur = it & 1;
    const int kpre = (kv + 64 <= last) ? kv + 64 : last;  // clamp tail prefetch
    stage_k(kpre, cur ^ 1);                               // +2 -> 6 outstanding
    asm volatile("s_waitcnt vmcnt(2)" ::: "memory");      // K(kv),V(kv) landed
    __builtin_amdgcn_s_barrier();                         // b1
    asm volatile("" ::: "memory");
    stage_v(kpre, cur ^ 1);  // +2 (Vl[cur^1] PV-reads all finished before b1)
    // ---- S = Q K^T (16 x 64) from LDS ----
    const u16* Kb = &Kl[cur][0];
    f32x4_t s[4] = {};
#pragma unroll
    for (int n = 0; n < 4; ++n) {
      const int row = n * 16 + lrow;
#pragma unroll
      for (int ks = 0; ks < 4; ++ks) {
        bf16x8_t bk = *reinterpret_cast<const bf16x8_t*>(
            Kb + row * 128 + (((ks << 2) | kg) ^ (row & 7)) * 8);
        s[n] = MFMA16(aq[ks], bk, s[n]);
      }
    }
    // ---- softmax: interior tiles need no mask (wave-uniform test) ----
    float ps[4][4];
    const bool interior = (kv + 63 <= qw) && ((qw + 15) - kv <= win);
    if (interior) {
#pragma unroll
      for (int n = 0; n < 4; ++n)
#pragma unroll
        for (int r = 0; r < 4; ++r)
          ps[n][r] = exp2f(__builtin_fmaf(s[n][r], SCALE_LOG2E, -FIXSUB));
    } else {
#pragma unroll
      for (int n = 0; n < 4; ++n) {
        const int key = kv + n * 16 + lrow;
#pragma unroll
        for (int r = 0; r < 4; ++r) {
          const int rowq = qw + kg * 4 + r;
          const bool ok = (key <= rowq) && (rowq - key <= win);
          ps[n][r] = ok ? exp2f(__builtin_fmaf(s[n][r], SCALE_LOG2E, -FIXSUB)) : 0.0f;
        }
      }
    }
#pragma unroll
    for (int r = 0; r < 4; ++r)
      lsum[r] += (ps[0][r] + ps[1][r]) + (ps[2][r] + ps[3][r]);
    // ---- P (bf16) -> swizzled per-wave LDS: D-frag -> A-frag layout ----
#pragma unroll
    for (int n = 0; n < 4; ++n)
#pragma unroll
      for (int r = 0; r < 4; ++r) {
        const int rp = kg * 4 + r;
        int bofs = rp * 128 + (n * 16 + lrow) * 2;
        bofs ^= (rp & 7) << 4;
        *reinterpret_cast<u16*>(reinterpret_cast<char*>(Pw) + bofs) = f2bf(ps[n][r]);
      }
    asm volatile("s_waitcnt lgkmcnt(0)" ::: "memory");
    __builtin_amdgcn_s_barrier();  // b2: QK reads of Kl[cur] done before next issueK
    asm volatile("" ::: "memory");
    // ---- O += P V ----
    bf16x8_t ap[2];
#pragma unroll
    for (int k2 = 0; k2 < 2; ++k2) {
      int bofs = lrow * 128 + k2 * 64 + kg * 16;
      bofs ^= (lrow & 7) << 4;
      ap[k2] = *reinterpret_cast<const bf16x8_t*>(reinterpret_cast<const char*>(Pw) + bofs);
    }
    const u16* Vb = &Vl[cur][0];
#pragma unroll
    for (int k2 = 0; k2 < 2; ++k2)
#pragma unroll
      for (int dn = 0; dn < 8; ++dn) {
        const int row = dn * 16 + lrow;
        bf16x8_t bv = *reinterpret_cast<const bf16x8_t*>(
            Vb + row * 64 + (((k2 << 2) | kg) ^ (row & 7)) * 8);
        accv[dn] = MFMA16(ap[k2], bv, accv[dn]);
      }
  }
  // ---- deferred row-sum reduce (within each 16-lane lrow group) ----
#pragma unroll
  for (int off = 1; off < 16; off <<= 1)
#pragma unroll
    for (int r = 0; r < 4; ++r) lsum[r] += __shfl_xor(lsum[r], off, 64);
  float inv[4];
#pragma unroll
  for (int r = 0; r < 4; ++r) inv[r] = 1.0f / lsum[r];
#pragma unroll
  for (int dn = 0; dn < 8; ++dn)
#pragma unroll
    for (int r = 0; r < 4; ++r) {
      const int rowg = b * TSEQ + qw + kg * 4 + r;
      const int col = h * HD + dn * 16 + lrow;
      yh[(size_t)rowg * HIDDEN + col] = f2bf(accv[dn][r] * inv[r]);
    }
}

extern "C" void kernel_launch(void* const* d_in, const int* in_sizes, int n_in, void* d_out,
                              int out_size, void* d_ws, size_t ws_size, hipStream_t stream) {
  const float* x = (const float*)d_in[0];
  const float* cosp = (const float*)d_in[1];
  const float* sinp = (const float*)d_in[2];
  const float* Wq = (const float*)d_in[3];
  const float* Wk = (const float*)d_in[4];
  const float* Wv = (const float*)d_in[5];
  const float* Wp = (const float*)d_in[6];
  const int* winp = (const int*)d_in[7];

  char* ws = (char*)d_ws;
  size_t off = 0;
  auto alloc = [&](size_t bytes) {
    char* p = ws + off;
    off += (bytes + 255) & ~(size_t)255;
    return p;
  };
  u16* xb = (u16*)alloc((size_t)NROWS * HIDDEN * 2);
  u16* wqb = (u16*)alloc((size_t)HIDDEN * HIDDEN * 2);
  u16* wkb = (u16*)alloc((size_t)HIDDEN * HIDDEN * 2);
  u16* wvb = (u16*)alloc((size_t)HIDDEN * HIDDEN * 2);
  u16* wpb = (u16*)alloc((size_t)HIDDEN * HIDDEN * 2);
  u16* qh = (u16*)alloc((size_t)NROWS * HIDDEN * 2);
  u16* kh = (u16*)alloc((size_t)NROWS * HIDDEN * 2);
  u16* vt = (u16*)alloc((size_t)NROWS * HIDDEN * 2);
  u16* yh = (u16*)alloc((size_t)NROWS * HIDDEN * 2);

  const int nx = NROWS * HIDDEN;   // 6291456
  const int nw = HIDDEN * HIDDEN;  // 2359296
  cast_kernel<<<nx / 1024, 256, 0, stream>>>(x, xb, nx);
  cast4_kernel<<<dim3(nw / 1024, 4), 256, 0, stream>>>(Wq, Wk, Wv, Wp, wqb, wkb, wvb, wpb, nw);

  gemm_qkv_kernel<<<dim3(1152), 256, 0, stream>>>(xb, wqb, wkb, wvb, cosp, sinp, qh, kh, vt);
  attn_kernel<<<dim3(384), 512, 0, stream>>>(qh, kh, vt, yh, winp);
  gemm_out_kernel<<<dim3(384), 256, 0, stream>>>(yh, wpb, (float*)d_out);
}